// Round 10
// baseline (140.872 us; speedup 1.0000x reference)
//
#include <hip/hip_runtime.h>

typedef short bf16x8_t __attribute__((ext_vector_type(8)));
typedef float f32x4_t __attribute__((ext_vector_type(4)));

__device__ __forceinline__ float bf2f(unsigned short h) {
  union { unsigned int u; float f; } v; v.u = ((unsigned int)h) << 16; return v.f;
}
__device__ __forceinline__ unsigned short f2bf(float f) {
  union { float f; unsigned int u; } v; v.f = f;
  unsigned int u = v.u + 0x7FFFu + ((v.u >> 16) & 1u);
  return (unsigned short)(u >> 16);
}
__device__ __forceinline__ unsigned int fbits(float f) {
  return __builtin_bit_cast(unsigned int, f);
}
// 2^x via v_exp_f32 directly (NOT __exp2f: glibc math.h macroizes that name
// on this toolchain and breaks the build -- round 9).
__device__ __forceinline__ float exp2_hw(float x) {
  return __builtin_amdgcn_exp2f(x);
}
// Pack high halves of two f32 into one u32 (truncation bf16 pair) in ONE
// VALU op: v_perm_b32 selects bytes {hi.b3,hi.b2,lo.b3,lo.b2}.
__device__ __forceinline__ unsigned int pack_trunc(float lo, float hi) {
  return __builtin_amdgcn_perm(fbits(hi), fbits(lo), 0x07060302u);
}
// Async global->LDS, 16 B per lane. HW writes wave-uniform LDS base +
// lane*16; the lds pointer must be the wave's slot base (uniform in-wave).
__device__ __forceinline__ void gload_lds16(const void* gsrc, void* ldst) {
  __builtin_amdgcn_global_load_lds(
      (const __attribute__((address_space(1))) unsigned int*)gsrc,
      (__attribute__((address_space(3))) unsigned int*)ldst, 16, 0, 0);
}

// Static device workspace. Inputs/outputs are f32 (confirmed round 3).
__device__ __align__(16) unsigned short g_hT[16 * 1024 * 256];     // GN out [b][n][c]; reused as attn OT
__device__ __align__(16) unsigned short g_qT[16 * 4 * 1024 * 64];  // [b][h][n][d] (PRE-SCALED by 0.125*log2e, round 12)
__device__ __align__(16) unsigned short g_kT[16 * 4 * 1024 * 64];  // [b][h][n][d]
__device__ __align__(16) unsigned short g_vN[16 * 4 * 64 * 1024];  // [b][h][d][n]
// Pre-converted bf16 weights (round 11): converted ONCE in gn_kernel.
__device__ __align__(16) unsigned short g_wq[768 * 256];
__device__ __align__(16) unsigned short g_wp[256 * 256];

// ---------------------------------------------------------------------------
// Kernel 1: GroupNorm.  x[b][c][n] f32 -> g_hT[b][n][c] bf16 (transposed)
// Also pre-converts qkv_w / proj_w to bf16 (2 elements per thread).
// ---------------------------------------------------------------------------
__global__ __launch_bounds__(256) void gn_kernel(
    const float* __restrict__ x, const float* __restrict__ gamma,
    const float* __restrict__ beta, const float* __restrict__ qkv_w,
    const float* __restrict__ proj_w) {
  const int b = blockIdx.x >> 5, g = blockIdx.x & 31;
  const int t = threadIdx.x;
  const float4* xg = (const float4*)(x + (size_t)(b * 256 + g * 8) * 1024);

  __shared__ __align__(16) unsigned short lds[8192];
  __shared__ float red[16];

  float vals[32];
  float s = 0.f, sq = 0.f;
#pragma unroll
  for (int p = 0; p < 4; ++p) {
    int idx = t + p * 256;
    float4 a = xg[2 * idx], c = xg[2 * idx + 1];
    float tmp[8] = {a.x, a.y, a.z, a.w, c.x, c.y, c.z, c.w};
#pragma unroll
    for (int j = 0; j < 8; ++j) {
      vals[p * 8 + j] = tmp[j];
      s += tmp[j]; sq += tmp[j] * tmp[j];
    }
  }

  // Weight pre-conversion: 512 blocks x 256 threads x 2 elems covers
  // 768*256 + 256*256 = 262144 elements exactly.
  {
    int widx = (blockIdx.x * 256 + t) * 2;
    const float* wsrc;
    unsigned short* wdst;
    if (widx < 196608) { wsrc = qkv_w + widx; wdst = g_wq + widx; }
    else { wsrc = proj_w + (widx - 196608); wdst = g_wp + (widx - 196608); }
    float2 wv = *(const float2*)wsrc;
    wdst[0] = f2bf(wv.x); wdst[1] = f2bf(wv.y);
  }

#pragma unroll
  for (int m = 32; m; m >>= 1) {
    s += __shfl_xor(s, m, 64);
    sq += __shfl_xor(sq, m, 64);
  }
  const int w = t >> 6;
  if ((t & 63) == 0) { red[w] = s; red[8 + w] = sq; }
  __syncthreads();
  s = red[0] + red[1] + red[2] + red[3];
  sq = red[8] + red[9] + red[10] + red[11];
  const float mu = s * (1.f / 8192.f);
  const float var = sq * (1.f / 8192.f) - mu * mu;
  const float rstd = rsqrtf(var + 1e-5f);

#pragma unroll
  for (int p = 0; p < 4; ++p) {
    int idx = t + p * 256;
    int c = idx >> 7;
    float ga = gamma[g * 8 + c] * rstd;
    float be = beta[g * 8 + c] - mu * ga;
    union { unsigned short u[8]; uint4 v; } pk;
#pragma unroll
    for (int j = 0; j < 8; ++j) pk.u[j] = f2bf(vals[p * 8 + j] * ga + be);
    ((uint4*)lds)[idx] = pk.v;
  }
  __syncthreads();

  unsigned short* dstbase = g_hT + (size_t)b * 1024 * 256 + g * 8;
#pragma unroll
  for (int p = 0; p < 4; ++p) {
    int n = t + p * 256;
    union { unsigned short u[8]; uint4 v; } pk;
#pragma unroll
    for (int c = 0; c < 8; ++c) pk.u[c] = lds[c * 1024 + n];
    *(uint4*)(dstbase + (size_t)n * 256) = pk.v;
  }
}

// ---------------------------------------------------------------------------
// Kernel 2: channel GEMM  C[o][n] = sum_k W[o][k] * hT[n][k]  (K = 256)
// Round 13 (measured -21 us): QKV 96x256 tiles grid (4,8,16); proj 64x128
// grid (8,4,16); both = 512 blocks = 2 blocks/CU.
// Round 16 (measured NEUTRAL, kept): staging via global_load_lds width=16,
// linear LDS dest + pre-swizzled global source, XOR'd fragment reads.
// ---------------------------------------------------------------------------
template <int MODE>
__global__ __launch_bounds__(256, 2) void gemm_ct(
    const float* __restrict__ bias, const float* __restrict__ xres,
    float* __restrict__ outp) {
  constexpr int OT = (MODE == 0) ? 96 : 64;    // output rows per block
  constexpr int NT = (MODE == 0) ? 256 : 128;  // n cols per block
  constexpr int OI = OT / 16;                  // row frags (6 / 4)
  constexpr int NJ = NT / 64;                  // col frags per wave (4 / 2)
  constexpr int ASL = OT * 8;                  // A uint4 slots per kb
  constexpr int BSL = NT * 8;                  // B uint4 slots per kb

  const int n0 = blockIdx.x * NT;
  const int oty = blockIdx.y, o0 = oty * OT;
  const int b = blockIdx.z;
  const int t = threadIdx.x;
  const int w = t >> 6, lane = t & 63, quad = lane >> 4, l15 = lane & 15;

  __shared__ uint4 as[ASL];  // [row][kc ^ (row&7)]
  __shared__ uint4 bs[BSL];  // [row][kc ^ (row&7)]

  const uint4* Bv = (const uint4*)g_hT;
  const unsigned short* Wb = (MODE == 0) ? g_wq : g_wp;

  f32x4_t acc[OI][NJ];
#pragma unroll
  for (int i = 0; i < OI; ++i)
#pragma unroll
    for (int j = 0; j < NJ; ++j) acc[i][j] = (f32x4_t){0.f, 0.f, 0.f, 0.f};

  for (int kb = 0; kb < 4; ++kb) {
#pragma unroll
    for (int p = 0; p < ASL / 256; ++p) {
      int L = p * 256 + t;
      int row = L >> 3, kc = (L & 7) ^ (row & 7);
      gload_lds16(Wb + (size_t)(o0 + row) * 256 + kb * 64 + kc * 8,
                  &as[p * 256 + w * 64]);
    }
#pragma unroll
    for (int p = 0; p < BSL / 256; ++p) {
      int L = p * 256 + t;
      int row = L >> 3, kc = (L & 7) ^ (row & 7);
      gload_lds16(&Bv[(size_t)(b * 1024 + n0 + row) * 32 + kb * 8 + kc],
                  &bs[p * 256 + w * 64]);
    }
    __syncthreads();  // drains vmcnt (global_load_lds) before reads
#pragma unroll
    for (int kk = 0; kk < 2; ++kk) {
      int ch = kk * 4 + quad;
      const int sw = ch ^ (l15 & 7);
      bf16x8_t af[OI];
#pragma unroll
      for (int i = 0; i < OI; ++i)
        af[i] = __builtin_bit_cast(bf16x8_t, as[(i * 16 + l15) * 8 + sw]);
#pragma unroll
      for (int j = 0; j < NJ; ++j) {
        bf16x8_t bf = __builtin_bit_cast(
            bf16x8_t, bs[(w * (NT / 4) + j * 16 + l15) * 8 + sw]);
#pragma unroll
        for (int i = 0; i < OI; ++i)
          acc[i][j] = __builtin_amdgcn_mfma_f32_16x16x32_bf16(af[i], bf, acc[i][j], 0, 0, 0);
      }
    }
    __syncthreads();
  }

  float bi[OI][4];
#pragma unroll
  for (int i = 0; i < OI; ++i)
#pragma unroll
    for (int r = 0; r < 4; ++r) bi[i][r] = bias[o0 + i * 16 + quad * 4 + r];

  if (MODE == 0) {
#pragma unroll
    for (int i = 0; i < OI; ++i) {
      const int r0 = o0 + i * 16;
      const int head = r0 / 192;
      const int win = r0 - head * 192;
      const int type = win >> 6;         // 0=q 1=k 2=v
      const int d0 = (win & 63) + quad * 4;
      if (type < 2) {
        // Q gets the softmax scale folded in at the source (round 12).
        const float sc = (type == 0) ? 0.18033688f : 1.0f;  // 0.125 * log2(e)
        unsigned short* dst = (type == 0 ? g_qT : g_kT) + (size_t)(b * 4 + head) * 65536;
#pragma unroll
        for (int j = 0; j < NJ; ++j) {
          int n = n0 + w * 64 + j * 16 + l15;
          ushort4 pk;
          pk.x = f2bf((acc[i][j][0] + bi[i][0]) * sc);
          pk.y = f2bf((acc[i][j][1] + bi[i][1]) * sc);
          pk.z = f2bf((acc[i][j][2] + bi[i][2]) * sc);
          pk.w = f2bf((acc[i][j][3] + bi[i][3]) * sc);
          *(ushort4*)(dst + (size_t)n * 64 + d0) = pk;
        }
      } else {
        unsigned short* dst = g_vN + (size_t)(b * 4 + head) * 65536;
#pragma unroll
        for (int j = 0; j < NJ; ++j) {
          int n = n0 + w * 64 + j * 16 + l15;
#pragma unroll
          for (int r = 0; r < 4; ++r)
            dst[(size_t)(d0 + r) * 1024 + n] = f2bf(acc[i][j][r] + bi[i][r]);
        }
      }
    }
  } else {
#pragma unroll
    for (int i = 0; i < OI; ++i)
#pragma unroll
      for (int r = 0; r < 4; ++r) {
        int c = o0 + i * 16 + quad * 4 + r;
        const float* xr = xres + (((size_t)b * 256 + c) << 10);
        float* op = outp + (((size_t)b * 256 + c) << 10);
#pragma unroll
        for (int j = 0; j < NJ; ++j) {
          int n = n0 + w * 32 + j * 16 + l15;
          op[n] = acc[i][j][r] + bi[i][r] + xr[n];
        }
      }
  }
}

// ---------------------------------------------------------------------------
// Kernel 3: flash attention, transposed-P.
// Round 17: occupancy push. QBLK 128->64 (one q-tile per block), grid
// (64,16) = 1024 blocks; single-buffered K/V LDS (8+8 KB) + Pt 9.2 KB =
// 25.2 KB -> 4 blocks/CU = 4 waves/SIMD (was 2). Rationale: staged attn
// measured ~32 us at ~7% MFMA duty -- latency/sync-bound at 2 waves/SIMD;
// KV re-reads are L2-resident (same-bh blocks land on same XCD: linear-id
// stride 64 == 0 mod 8). Single buffer needs 2 barriers/iter but 4
// co-resident blocks keep the CU fed. Softmax diet kept (r10/12).
// absmax 0.03125 << 0.1006 threshold.
// ---------------------------------------------------------------------------
__global__ __launch_bounds__(256, 4) void attn_kernel() {
  const int bh = blockIdx.x;
  const int n0 = blockIdx.y * 64;
  const int t = threadIdx.x;
  const int w = t >> 6, lane = t & 63, quad = lane >> 4, l15 = lane & 15;
  const int b = bh >> 2, h = bh & 3;

  const uint4* qv = (const uint4*)(g_qT + (size_t)bh * 65536);
  const uint4* kv = (const uint4*)(g_kT + (size_t)bh * 65536);
  const uint4* vv = (const uint4*)(g_vN + (size_t)bh * 65536);

  __shared__ uint4 ks[512];  // [chunk][row^chunk]  XOR-swizzled, single buffer
  __shared__ uint4 vs[512];
  __shared__ __align__(16) unsigned short Pt[4 * 16 * 72];  // [wave][qrow][m']

  uint4 qr[2];
#pragma unroll
  for (int kk = 0; kk < 2; ++kk)
    qr[kk] = qv[(size_t)(n0 + w * 16 + l15) * 8 + kk * 4 + quad];

  const int rr0 = t >> 3, cc = t & 7, rr1 = rr0 + 32;
  uint4 kr0 = kv[rr0 * 8 + cc], kr1 = kv[rr1 * 8 + cc];
  uint4 vr0 = vv[rr0 * 128 + cc], vr1 = vv[rr1 * 128 + cc];

  f32x4_t OA[4];
#pragma unroll
  for (int i = 0; i < 4; ++i) OA[i] = (f32x4_t){0.f, 0.f, 0.f, 0.f};
  float rsum = 0.f;

  unsigned short* Pw = Pt + w * 1152;

#pragma unroll 1
  for (int mt = 0; mt < 16; ++mt) {
    ks[cc * 64 + (rr0 ^ cc)] = kr0; ks[cc * 64 + (rr1 ^ cc)] = kr1;
    vs[cc * 64 + (rr0 ^ cc)] = vr0; vs[cc * 64 + (rr1 ^ cc)] = vr1;
    __syncthreads();  // staged tile visible

    if (mt < 15) {
      int m1 = (mt + 1) * 64;
      kr0 = kv[(m1 + rr0) * 8 + cc]; kr1 = kv[(m1 + rr1) * 8 + cc];
      vr0 = vv[rr0 * 128 + (mt + 1) * 8 + cc]; vr1 = vv[rr1 * 128 + (mt + 1) * 8 + cc];
    }

    f32x4_t sA[4];
#pragma unroll
    for (int i = 0; i < 4; ++i) sA[i] = (f32x4_t){0.f, 0.f, 0.f, 0.f};
#pragma unroll
    for (int kk = 0; kk < 2; ++kk) {
      int ch = kk * 4 + quad;
      bf16x8_t bq = __builtin_bit_cast(bf16x8_t, qr[kk]);
#pragma unroll
      for (int ms = 0; ms < 4; ++ms) {
        bf16x8_t ak = __builtin_bit_cast(bf16x8_t, ks[ch * 64 + ((ms * 16 + l15) ^ ch)]);
        sA[ms] = __builtin_amdgcn_mfma_f32_16x16x32_bf16(ak, bq, sA[ms], 0, 0, 0);
      }
    }

    // p = exp2(s) (Q pre-scaled); truncation-pack pairs via v_perm;
    // full-precision row sums.
#pragma unroll
    for (int ms = 0; ms < 4; ++ms) {
      float a0 = exp2_hw(sA[ms][0]), a1 = exp2_hw(sA[ms][1]);
      float a2 = exp2_hw(sA[ms][2]), a3 = exp2_hw(sA[ms][3]);
      rsum += (a0 + a1) + (a2 + a3);
      uint2 pA;
      pA.x = pack_trunc(a0, a1);
      pA.y = pack_trunc(a2, a3);
      *(uint2*)(Pw + l15 * 72 + ms * 16 + quad * 4) = pA;
    }

#pragma unroll
    for (int km = 0; km < 2; ++km) {
      int ch = km * 4 + quad;
      bf16x8_t bp = *(const bf16x8_t*)(Pw + l15 * 72 + km * 32 + quad * 8);
#pragma unroll
      for (int ds = 0; ds < 4; ++ds) {
        bf16x8_t av = __builtin_bit_cast(bf16x8_t, vs[ch * 64 + ((ds * 16 + l15) ^ ch)]);
        OA[ds] = __builtin_amdgcn_mfma_f32_16x16x32_bf16(av, bp, OA[ds], 0, 0, 0);
      }
    }
    __syncthreads();  // all reads done before next stage overwrites
  }

  rsum += __shfl_xor(rsum, 16, 64);
  rsum += __shfl_xor(rsum, 32, 64);
  const float inv = 1.f / rsum;

  unsigned short* dstA = g_hT + ((size_t)b * 1024 + n0 + w * 16 + l15) * 256 + h * 64;
#pragma unroll
  for (int ds = 0; ds < 4; ++ds) {
    ushort4 pk;
    pk.x = f2bf(OA[ds][0] * inv); pk.y = f2bf(OA[ds][1] * inv);
    pk.z = f2bf(OA[ds][2] * inv); pk.w = f2bf(OA[ds][3] * inv);
    *(ushort4*)(dstA + ds * 16 + quad * 4) = pk;
  }
}

// ---------------------------------------------------------------------------
extern "C" void kernel_launch(void* const* d_in, const int* in_sizes, int n_in,
                              void* d_out, int out_size, void* d_ws, size_t ws_size,
                              hipStream_t stream) {
  const float* x = (const float*)d_in[0];
  const float* gam = (const float*)d_in[1];
  const float* bet = (const float*)d_in[2];
  const float* qkv_w = (const float*)d_in[3];
  const float* qkv_b = (const float*)d_in[4];
  const float* pr_w = (const float*)d_in[5];
  const float* pr_b = (const float*)d_in[6];
  float* out = (float*)d_out;

  gn_kernel<<<512, 256, 0, stream>>>(x, gam, bet, qkv_w, pr_w);
  gemm_ct<0><<<dim3(4, 8, 16), 256, 0, stream>>>(qkv_b, nullptr, nullptr);
  attn_kernel<<<dim3(64, 16), 256, 0, stream>>>();
  gemm_ct<1><<<dim3(8, 4, 16), 256, 0, stream>>>(pr_b, x, out);
}

// Round 11
// 138.590 us; speedup vs baseline: 1.0165x; 1.0165x over previous
//
#include <hip/hip_runtime.h>

typedef short bf16x8_t __attribute__((ext_vector_type(8)));
typedef float f32x4_t __attribute__((ext_vector_type(4)));

__device__ __forceinline__ float bf2f(unsigned short h) {
  union { unsigned int u; float f; } v; v.u = ((unsigned int)h) << 16; return v.f;
}
__device__ __forceinline__ unsigned short f2bf(float f) {
  union { float f; unsigned int u; } v; v.f = f;
  unsigned int u = v.u + 0x7FFFu + ((v.u >> 16) & 1u);
  return (unsigned short)(u >> 16);
}
__device__ __forceinline__ unsigned int fbits(float f) {
  return __builtin_bit_cast(unsigned int, f);
}
// 2^x via v_exp_f32 directly (NOT __exp2f: glibc math.h macroizes that name
// on this toolchain and breaks the build -- round 9).
__device__ __forceinline__ float exp2_hw(float x) {
  return __builtin_amdgcn_exp2f(x);
}
// Pack high halves of two f32 into one u32 (truncation bf16 pair) in ONE
// VALU op: v_perm_b32 selects bytes {hi.b3,hi.b2,lo.b3,lo.b2}.
__device__ __forceinline__ unsigned int pack_trunc(float lo, float hi) {
  return __builtin_amdgcn_perm(fbits(hi), fbits(lo), 0x07060302u);
}
// Async global->LDS, 16 B per lane. HW writes wave-uniform LDS base +
// lane*16; the lds pointer must be the wave's slot base (uniform in-wave).
__device__ __forceinline__ void gload_lds16(const void* gsrc, void* ldst) {
  __builtin_amdgcn_global_load_lds(
      (const __attribute__((address_space(1))) unsigned int*)gsrc,
      (__attribute__((address_space(3))) unsigned int*)ldst, 16, 0, 0);
}

// Static device workspace. Inputs/outputs are f32 (confirmed round 3).
__device__ __align__(16) unsigned short g_hT[16 * 1024 * 256];     // GN out [b][n][c]; reused as attn OT
__device__ __align__(16) unsigned short g_qT[16 * 4 * 1024 * 64];  // [b][h][n][d] (PRE-SCALED by 0.125*log2e, round 12)
__device__ __align__(16) unsigned short g_kT[16 * 4 * 1024 * 64];  // [b][h][n][d]
__device__ __align__(16) unsigned short g_vN[16 * 4 * 64 * 1024];  // [b][h][d][n]
// Pre-converted bf16 weights (round 11): converted ONCE in gn_kernel.
__device__ __align__(16) unsigned short g_wq[768 * 256];
__device__ __align__(16) unsigned short g_wp[256 * 256];

// ---------------------------------------------------------------------------
// Kernel 1: GroupNorm.  x[b][c][n] f32 -> g_hT[b][n][c] bf16 (transposed)
// Also pre-converts qkv_w / proj_w to bf16 (2 elements per thread).
// ---------------------------------------------------------------------------
__global__ __launch_bounds__(256) void gn_kernel(
    const float* __restrict__ x, const float* __restrict__ gamma,
    const float* __restrict__ beta, const float* __restrict__ qkv_w,
    const float* __restrict__ proj_w) {
  const int b = blockIdx.x >> 5, g = blockIdx.x & 31;
  const int t = threadIdx.x;
  const float4* xg = (const float4*)(x + (size_t)(b * 256 + g * 8) * 1024);

  __shared__ __align__(16) unsigned short lds[8192];
  __shared__ float red[16];

  float vals[32];
  float s = 0.f, sq = 0.f;
#pragma unroll
  for (int p = 0; p < 4; ++p) {
    int idx = t + p * 256;
    float4 a = xg[2 * idx], c = xg[2 * idx + 1];
    float tmp[8] = {a.x, a.y, a.z, a.w, c.x, c.y, c.z, c.w};
#pragma unroll
    for (int j = 0; j < 8; ++j) {
      vals[p * 8 + j] = tmp[j];
      s += tmp[j]; sq += tmp[j] * tmp[j];
    }
  }

  // Weight pre-conversion: 512 blocks x 256 threads x 2 elems covers
  // 768*256 + 256*256 = 262144 elements exactly.
  {
    int widx = (blockIdx.x * 256 + t) * 2;
    const float* wsrc;
    unsigned short* wdst;
    if (widx < 196608) { wsrc = qkv_w + widx; wdst = g_wq + widx; }
    else { wsrc = proj_w + (widx - 196608); wdst = g_wp + (widx - 196608); }
    float2 wv = *(const float2*)wsrc;
    wdst[0] = f2bf(wv.x); wdst[1] = f2bf(wv.y);
  }

#pragma unroll
  for (int m = 32; m; m >>= 1) {
    s += __shfl_xor(s, m, 64);
    sq += __shfl_xor(sq, m, 64);
  }
  const int w = t >> 6;
  if ((t & 63) == 0) { red[w] = s; red[8 + w] = sq; }
  __syncthreads();
  s = red[0] + red[1] + red[2] + red[3];
  sq = red[8] + red[9] + red[10] + red[11];
  const float mu = s * (1.f / 8192.f);
  const float var = sq * (1.f / 8192.f) - mu * mu;
  const float rstd = rsqrtf(var + 1e-5f);

#pragma unroll
  for (int p = 0; p < 4; ++p) {
    int idx = t + p * 256;
    int c = idx >> 7;
    float ga = gamma[g * 8 + c] * rstd;
    float be = beta[g * 8 + c] - mu * ga;
    union { unsigned short u[8]; uint4 v; } pk;
#pragma unroll
    for (int j = 0; j < 8; ++j) pk.u[j] = f2bf(vals[p * 8 + j] * ga + be);
    ((uint4*)lds)[idx] = pk.v;
  }
  __syncthreads();

  unsigned short* dstbase = g_hT + (size_t)b * 1024 * 256 + g * 8;
#pragma unroll
  for (int p = 0; p < 4; ++p) {
    int n = t + p * 256;
    union { unsigned short u[8]; uint4 v; } pk;
#pragma unroll
    for (int c = 0; c < 8; ++c) pk.u[c] = lds[c * 1024 + n];
    *(uint4*)(dstbase + (size_t)n * 256) = pk.v;
  }
}

// ---------------------------------------------------------------------------
// Kernel 2: channel GEMM  C[o][n] = sum_k W[o][k] * hT[n][k]  (K = 256)
// Round 13 (measured -21 us): QKV 96x256 tiles grid (4,8,16); proj 64x128
// grid (8,4,16); both = 512 blocks = 2 blocks/CU.
// Round 16 (measured NEUTRAL, kept): staging via global_load_lds width=16,
// linear LDS dest + pre-swizzled global source, XOR'd fragment reads.
// ---------------------------------------------------------------------------
template <int MODE>
__global__ __launch_bounds__(256, 2) void gemm_ct(
    const float* __restrict__ bias, const float* __restrict__ xres,
    float* __restrict__ outp) {
  constexpr int OT = (MODE == 0) ? 96 : 64;    // output rows per block
  constexpr int NT = (MODE == 0) ? 256 : 128;  // n cols per block
  constexpr int OI = OT / 16;                  // row frags (6 / 4)
  constexpr int NJ = NT / 64;                  // col frags per wave (4 / 2)
  constexpr int ASL = OT * 8;                  // A uint4 slots per kb
  constexpr int BSL = NT * 8;                  // B uint4 slots per kb

  const int n0 = blockIdx.x * NT;
  const int oty = blockIdx.y, o0 = oty * OT;
  const int b = blockIdx.z;
  const int t = threadIdx.x;
  const int w = t >> 6, lane = t & 63, quad = lane >> 4, l15 = lane & 15;

  __shared__ uint4 as[ASL];  // [row][kc ^ (row&7)]
  __shared__ uint4 bs[BSL];  // [row][kc ^ (row&7)]

  const uint4* Bv = (const uint4*)g_hT;
  const unsigned short* Wb = (MODE == 0) ? g_wq : g_wp;

  f32x4_t acc[OI][NJ];
#pragma unroll
  for (int i = 0; i < OI; ++i)
#pragma unroll
    for (int j = 0; j < NJ; ++j) acc[i][j] = (f32x4_t){0.f, 0.f, 0.f, 0.f};

  for (int kb = 0; kb < 4; ++kb) {
#pragma unroll
    for (int p = 0; p < ASL / 256; ++p) {
      int L = p * 256 + t;
      int row = L >> 3, kc = (L & 7) ^ (row & 7);
      gload_lds16(Wb + (size_t)(o0 + row) * 256 + kb * 64 + kc * 8,
                  &as[p * 256 + w * 64]);
    }
#pragma unroll
    for (int p = 0; p < BSL / 256; ++p) {
      int L = p * 256 + t;
      int row = L >> 3, kc = (L & 7) ^ (row & 7);
      gload_lds16(&Bv[(size_t)(b * 1024 + n0 + row) * 32 + kb * 8 + kc],
                  &bs[p * 256 + w * 64]);
    }
    __syncthreads();  // drains vmcnt (global_load_lds) before reads
#pragma unroll
    for (int kk = 0; kk < 2; ++kk) {
      int ch = kk * 4 + quad;
      const int sw = ch ^ (l15 & 7);
      bf16x8_t af[OI];
#pragma unroll
      for (int i = 0; i < OI; ++i)
        af[i] = __builtin_bit_cast(bf16x8_t, as[(i * 16 + l15) * 8 + sw]);
#pragma unroll
      for (int j = 0; j < NJ; ++j) {
        bf16x8_t bf = __builtin_bit_cast(
            bf16x8_t, bs[(w * (NT / 4) + j * 16 + l15) * 8 + sw]);
#pragma unroll
        for (int i = 0; i < OI; ++i)
          acc[i][j] = __builtin_amdgcn_mfma_f32_16x16x32_bf16(af[i], bf, acc[i][j], 0, 0, 0);
      }
    }
    __syncthreads();
  }

  float bi[OI][4];
#pragma unroll
  for (int i = 0; i < OI; ++i)
#pragma unroll
    for (int r = 0; r < 4; ++r) bi[i][r] = bias[o0 + i * 16 + quad * 4 + r];

  if (MODE == 0) {
#pragma unroll
    for (int i = 0; i < OI; ++i) {
      const int r0 = o0 + i * 16;
      const int head = r0 / 192;
      const int win = r0 - head * 192;
      const int type = win >> 6;         // 0=q 1=k 2=v
      const int d0 = (win & 63) + quad * 4;
      if (type < 2) {
        // Q gets the softmax scale folded in at the source (round 12).
        const float sc = (type == 0) ? 0.18033688f : 1.0f;  // 0.125 * log2(e)
        unsigned short* dst = (type == 0 ? g_qT : g_kT) + (size_t)(b * 4 + head) * 65536;
#pragma unroll
        for (int j = 0; j < NJ; ++j) {
          int n = n0 + w * 64 + j * 16 + l15;
          ushort4 pk;
          pk.x = f2bf((acc[i][j][0] + bi[i][0]) * sc);
          pk.y = f2bf((acc[i][j][1] + bi[i][1]) * sc);
          pk.z = f2bf((acc[i][j][2] + bi[i][2]) * sc);
          pk.w = f2bf((acc[i][j][3] + bi[i][3]) * sc);
          *(ushort4*)(dst + (size_t)n * 64 + d0) = pk;
        }
      } else {
        unsigned short* dst = g_vN + (size_t)(b * 4 + head) * 65536;
#pragma unroll
        for (int j = 0; j < NJ; ++j) {
          int n = n0 + w * 64 + j * 16 + l15;
#pragma unroll
          for (int r = 0; r < 4; ++r)
            dst[(size_t)(d0 + r) * 1024 + n] = f2bf(acc[i][j][r] + bi[i][r]);
        }
      }
    }
  } else {
#pragma unroll
    for (int i = 0; i < OI; ++i)
#pragma unroll
      for (int r = 0; r < 4; ++r) {
        int c = o0 + i * 16 + quad * 4 + r;
        const float* xr = xres + (((size_t)b * 256 + c) << 10);
        float* op = outp + (((size_t)b * 256 + c) << 10);
#pragma unroll
        for (int j = 0; j < NJ; ++j) {
          int n = n0 + w * 32 + j * 16 + l15;
          op[n] = acc[i][j][r] + bi[i][r] + xr[n];
        }
      }
  }
}

// ---------------------------------------------------------------------------
// Kernel 3: flash attention, transposed-P, two q-tiles per block.
// Round 18: REVERTED round-17 occupancy push (QBLK 64 measured +4.4 us:
// halved K/V reuse per staged byte + 2 barriers/iter beat the TLP gain).
// Back to QBLK 128, double-buffered K, 1 barrier/iter -- PLUS a one-tile
// software pipeline: iteration mt runs QK^T(mt) then PV(mt-1) then
// softmax(mt). Two independent MFMA streams per iteration cover the
// Pt write->read round-trip and exp chain (the ~4x stall at 2 waves/SIMD).
// PV(mt-1) reads Pt BEFORE softmax(mt) overwrites it (Pt is wave-private;
// same-wave LDS anti-dependency, compiler-ordered, no barrier). V gets a
// third buffer: slot written at iter mt is read at iter mt+1 and not
// rewritten until iter mt+3 (>= 2 barriers after the read). LDS 58 KB.
// absmax 0.03125 << 0.1006 threshold.
// ---------------------------------------------------------------------------
__global__ __launch_bounds__(256) void attn_kernel() {
  const int bh = blockIdx.x;
  const int n0 = blockIdx.y * 128;
  const int t = threadIdx.x;
  const int w = t >> 6, lane = t & 63, quad = lane >> 4, l15 = lane & 15;
  const int b = bh >> 2, h = bh & 3;

  const uint4* qv = (const uint4*)(g_qT + (size_t)bh * 65536);
  const uint4* kv = (const uint4*)(g_kT + (size_t)bh * 65536);
  const uint4* vv = (const uint4*)(g_vN + (size_t)bh * 65536);

  __shared__ uint4 ks[2][512];  // [parity][row^chunk]  XOR-swizzled
  __shared__ uint4 vs[3][512];  // [slot][row^chunk]    XOR-swizzled
  __shared__ __align__(16) unsigned short Pt[2 * 4 * 16 * 72];  // [AB][wave][qrow][m']

  uint4 qrA[2], qrB[2];
#pragma unroll
  for (int kk = 0; kk < 2; ++kk) {
    qrA[kk] = qv[(size_t)(n0 + w * 16 + l15) * 8 + kk * 4 + quad];
    qrB[kk] = qv[(size_t)(n0 + 64 + w * 16 + l15) * 8 + kk * 4 + quad];
  }

  const int rr0 = t >> 3, cc = t & 7, rr1 = rr0 + 32;
  uint4 kr0 = kv[rr0 * 8 + cc], kr1 = kv[rr1 * 8 + cc];
  uint4 vr0 = vv[rr0 * 128 + cc], vr1 = vv[rr1 * 128 + cc];

  f32x4_t OA[4], OB[4];
#pragma unroll
  for (int i = 0; i < 4; ++i) {
    OA[i] = (f32x4_t){0.f, 0.f, 0.f, 0.f};
    OB[i] = (f32x4_t){0.f, 0.f, 0.f, 0.f};
  }
  float rsumA = 0.f, rsumB = 0.f;

  unsigned short* PwA = Pt + w * 1152;
  unsigned short* PwB = Pt + 4608 + w * 1152;

  int vcur = 0, vprev = 2;

#pragma unroll 1
  for (int mt = 0; mt < 16; ++mt) {
    uint4* kb = ks[mt & 1];
    uint4* vb = vs[vcur];
    kb[cc * 64 + (rr0 ^ cc)] = kr0; kb[cc * 64 + (rr1 ^ cc)] = kr1;
    vb[cc * 64 + (rr0 ^ cc)] = vr0; vb[cc * 64 + (rr1 ^ cc)] = vr1;
    __syncthreads();  // the ONLY barrier per iteration

    if (mt < 15) {
      int m1 = (mt + 1) * 64;
      kr0 = kv[(m1 + rr0) * 8 + cc]; kr1 = kv[(m1 + rr1) * 8 + cc];
      vr0 = vv[rr0 * 128 + (mt + 1) * 8 + cc]; vr1 = vv[rr1 * 128 + (mt + 1) * 8 + cc];
    }

    // ---- QK^T(mt) ----
    f32x4_t sA[4], sB[4];
#pragma unroll
    for (int i = 0; i < 4; ++i) {
      sA[i] = (f32x4_t){0.f, 0.f, 0.f, 0.f};
      sB[i] = (f32x4_t){0.f, 0.f, 0.f, 0.f};
    }
#pragma unroll
    for (int kk = 0; kk < 2; ++kk) {
      int ch = kk * 4 + quad;
      bf16x8_t bqA = __builtin_bit_cast(bf16x8_t, qrA[kk]);
      bf16x8_t bqB = __builtin_bit_cast(bf16x8_t, qrB[kk]);
#pragma unroll
      for (int ms = 0; ms < 4; ++ms) {
        bf16x8_t ak = __builtin_bit_cast(bf16x8_t, kb[ch * 64 + ((ms * 16 + l15) ^ ch)]);
        sA[ms] = __builtin_amdgcn_mfma_f32_16x16x32_bf16(ak, bqA, sA[ms], 0, 0, 0);
        sB[ms] = __builtin_amdgcn_mfma_f32_16x16x32_bf16(ak, bqB, sB[ms], 0, 0, 0);
      }
    }

    // ---- PV(mt-1): read old Pt/V BEFORE softmax overwrites Pt ----
    if (mt > 0) {
      const uint4* vbp = vs[vprev];
#pragma unroll
      for (int km = 0; km < 2; ++km) {
        int ch = km * 4 + quad;
        bf16x8_t bpA = *(const bf16x8_t*)(PwA + l15 * 72 + km * 32 + quad * 8);
        bf16x8_t bpB = *(const bf16x8_t*)(PwB + l15 * 72 + km * 32 + quad * 8);
#pragma unroll
        for (int ds = 0; ds < 4; ++ds) {
          bf16x8_t av = __builtin_bit_cast(bf16x8_t, vbp[ch * 64 + ((ds * 16 + l15) ^ ch)]);
          OA[ds] = __builtin_amdgcn_mfma_f32_16x16x32_bf16(av, bpA, OA[ds], 0, 0, 0);
          OB[ds] = __builtin_amdgcn_mfma_f32_16x16x32_bf16(av, bpB, OB[ds], 0, 0, 0);
        }
      }
    }

    // ---- softmax(mt): p = exp2(s) (Q pre-scaled); v_perm pack; write Pt ----
#pragma unroll
    for (int ms = 0; ms < 4; ++ms) {
      float a0 = exp2_hw(sA[ms][0]), a1 = exp2_hw(sA[ms][1]);
      float a2 = exp2_hw(sA[ms][2]), a3 = exp2_hw(sA[ms][3]);
      float b0 = exp2_hw(sB[ms][0]), b1 = exp2_hw(sB[ms][1]);
      float b2 = exp2_hw(sB[ms][2]), b3 = exp2_hw(sB[ms][3]);
      rsumA += (a0 + a1) + (a2 + a3);
      rsumB += (b0 + b1) + (b2 + b3);
      uint2 pA, pB;
      pA.x = pack_trunc(a0, a1);
      pA.y = pack_trunc(a2, a3);
      pB.x = pack_trunc(b0, b1);
      pB.y = pack_trunc(b2, b3);
      *(uint2*)(PwA + l15 * 72 + ms * 16 + quad * 4) = pA;
      *(uint2*)(PwB + l15 * 72 + ms * 16 + quad * 4) = pB;
    }

    vprev = vcur; vcur = (vcur == 2) ? 0 : vcur + 1;
  }

  // ---- epilogue: PV(15) ----
  {
    const uint4* vbp = vs[vprev];
#pragma unroll
    for (int km = 0; km < 2; ++km) {
      int ch = km * 4 + quad;
      bf16x8_t bpA = *(const bf16x8_t*)(PwA + l15 * 72 + km * 32 + quad * 8);
      bf16x8_t bpB = *(const bf16x8_t*)(PwB + l15 * 72 + km * 32 + quad * 8);
#pragma unroll
      for (int ds = 0; ds < 4; ++ds) {
        bf16x8_t av = __builtin_bit_cast(bf16x8_t, vbp[ch * 64 + ((ds * 16 + l15) ^ ch)]);
        OA[ds] = __builtin_amdgcn_mfma_f32_16x16x32_bf16(av, bpA, OA[ds], 0, 0, 0);
        OB[ds] = __builtin_amdgcn_mfma_f32_16x16x32_bf16(av, bpB, OB[ds], 0, 0, 0);
      }
    }
  }

  rsumA += __shfl_xor(rsumA, 16, 64);
  rsumA += __shfl_xor(rsumA, 32, 64);
  rsumB += __shfl_xor(rsumB, 16, 64);
  rsumB += __shfl_xor(rsumB, 32, 64);
  const float invA = 1.f / rsumA, invB = 1.f / rsumB;

  unsigned short* dstA = g_hT + ((size_t)b * 1024 + n0 + w * 16 + l15) * 256 + h * 64;
  unsigned short* dstB = dstA + (size_t)64 * 256;
#pragma unroll
  for (int ds = 0; ds < 4; ++ds) {
    ushort4 pkA, pkB;
    pkA.x = f2bf(OA[ds][0] * invA); pkA.y = f2bf(OA[ds][1] * invA);
    pkA.z = f2bf(OA[ds][2] * invA); pkA.w = f2bf(OA[ds][3] * invA);
    pkB.x = f2bf(OB[ds][0] * invB); pkB.y = f2bf(OB[ds][1] * invB);
    pkB.z = f2bf(OB[ds][2] * invB); pkB.w = f2bf(OB[ds][3] * invB);
    *(ushort4*)(dstA + ds * 16 + quad * 4) = pkA;
    *(ushort4*)(dstB + ds * 16 + quad * 4) = pkB;
  }
}

// ---------------------------------------------------------------------------
extern "C" void kernel_launch(void* const* d_in, const int* in_sizes, int n_in,
                              void* d_out, int out_size, void* d_ws, size_t ws_size,
                              hipStream_t stream) {
  const float* x = (const float*)d_in[0];
  const float* gam = (const float*)d_in[1];
  const float* bet = (const float*)d_in[2];
  const float* qkv_w = (const float*)d_in[3];
  const float* qkv_b = (const float*)d_in[4];
  const float* pr_w = (const float*)d_in[5];
  const float* pr_b = (const float*)d_in[6];
  float* out = (float*)d_out;

  gn_kernel<<<512, 256, 0, stream>>>(x, gam, bet, qkv_w, pr_w);
  gemm_ct<0><<<dim3(4, 8, 16), 256, 0, stream>>>(qkv_b, nullptr, nullptr);
  attn_kernel<<<dim3(64, 8), 256, 0, stream>>>();
  gemm_ct<1><<<dim3(8, 4, 16), 256, 0, stream>>>(pr_b, x, out);
}

// Round 13
// 136.608 us; speedup vs baseline: 1.0312x; 1.0145x over previous
//
#include <hip/hip_runtime.h>

typedef short bf16x8_t __attribute__((ext_vector_type(8)));
typedef float f32x4_t __attribute__((ext_vector_type(4)));

__device__ __forceinline__ float bf2f(unsigned short h) {
  union { unsigned int u; float f; } v; v.u = ((unsigned int)h) << 16; return v.f;
}
__device__ __forceinline__ unsigned short f2bf(float f) {
  union { float f; unsigned int u; } v; v.f = f;
  unsigned int u = v.u + 0x7FFFu + ((v.u >> 16) & 1u);
  return (unsigned short)(u >> 16);
}
__device__ __forceinline__ unsigned int fbits(float f) {
  return __builtin_bit_cast(unsigned int, f);
}
// 2^x via v_exp_f32 directly (NOT __exp2f: glibc math.h macroizes that name
// on this toolchain and breaks the build -- round 9).
__device__ __forceinline__ float exp2_hw(float x) {
  return __builtin_amdgcn_exp2f(x);
}
// Pack high halves of two f32 into one u32 (truncation bf16 pair) in ONE
// VALU op: v_perm_b32 selects bytes {hi.b3,hi.b2,lo.b3,lo.b2}.
__device__ __forceinline__ unsigned int pack_trunc(float lo, float hi) {
  return __builtin_amdgcn_perm(fbits(hi), fbits(lo), 0x07060302u);
}
// Async global->LDS, 16 B per lane. HW writes wave-uniform LDS base +
// lane*16; the lds pointer must be the wave's slot base (uniform in-wave).
__device__ __forceinline__ void gload_lds16(const void* gsrc, void* ldst) {
  __builtin_amdgcn_global_load_lds(
      (const __attribute__((address_space(1))) unsigned int*)gsrc,
      (__attribute__((address_space(3))) unsigned int*)ldst, 16, 0, 0);
}

// Static device workspace. Inputs/outputs are f32 (confirmed round 3).
__device__ __align__(16) unsigned short g_hT[16 * 1024 * 256];     // GN out [b][n][c]; reused as attn OT
__device__ __align__(16) unsigned short g_qT[16 * 4 * 1024 * 64];  // [b][h][n][d] (PRE-SCALED by 0.125*log2e, round 12)
__device__ __align__(16) unsigned short g_kT[16 * 4 * 1024 * 64];  // [b][h][n][d]
__device__ __align__(16) unsigned short g_vN[16 * 4 * 64 * 1024];  // [b][h][d][n]
// Pre-converted bf16 weights (round 11): converted ONCE in gn_kernel.
__device__ __align__(16) unsigned short g_wq[768 * 256];
__device__ __align__(16) unsigned short g_wp[256 * 256];

// ---------------------------------------------------------------------------
// Kernel 1: GroupNorm.  x[b][c][n] f32 -> g_hT[b][n][c] bf16 (transposed)
// Also pre-converts qkv_w / proj_w to bf16 (2 elements per thread).
// ---------------------------------------------------------------------------
__global__ __launch_bounds__(256) void gn_kernel(
    const float* __restrict__ x, const float* __restrict__ gamma,
    const float* __restrict__ beta, const float* __restrict__ qkv_w,
    const float* __restrict__ proj_w) {
  const int b = blockIdx.x >> 5, g = blockIdx.x & 31;
  const int t = threadIdx.x;
  const float4* xg = (const float4*)(x + (size_t)(b * 256 + g * 8) * 1024);

  __shared__ __align__(16) unsigned short lds[8192];
  __shared__ float red[16];

  float vals[32];
  float s = 0.f, sq = 0.f;
#pragma unroll
  for (int p = 0; p < 4; ++p) {
    int idx = t + p * 256;
    float4 a = xg[2 * idx], c = xg[2 * idx + 1];
    float tmp[8] = {a.x, a.y, a.z, a.w, c.x, c.y, c.z, c.w};
#pragma unroll
    for (int j = 0; j < 8; ++j) {
      vals[p * 8 + j] = tmp[j];
      s += tmp[j]; sq += tmp[j] * tmp[j];
    }
  }

  // Weight pre-conversion: 512 blocks x 256 threads x 2 elems covers
  // 768*256 + 256*256 = 262144 elements exactly.
  {
    int widx = (blockIdx.x * 256 + t) * 2;
    const float* wsrc;
    unsigned short* wdst;
    if (widx < 196608) { wsrc = qkv_w + widx; wdst = g_wq + widx; }
    else { wsrc = proj_w + (widx - 196608); wdst = g_wp + (widx - 196608); }
    float2 wv = *(const float2*)wsrc;
    wdst[0] = f2bf(wv.x); wdst[1] = f2bf(wv.y);
  }

#pragma unroll
  for (int m = 32; m; m >>= 1) {
    s += __shfl_xor(s, m, 64);
    sq += __shfl_xor(sq, m, 64);
  }
  const int w = t >> 6;
  if ((t & 63) == 0) { red[w] = s; red[8 + w] = sq; }
  __syncthreads();
  s = red[0] + red[1] + red[2] + red[3];
  sq = red[8] + red[9] + red[10] + red[11];
  const float mu = s * (1.f / 8192.f);
  const float var = sq * (1.f / 8192.f) - mu * mu;
  const float rstd = rsqrtf(var + 1e-5f);

#pragma unroll
  for (int p = 0; p < 4; ++p) {
    int idx = t + p * 256;
    int c = idx >> 7;
    float ga = gamma[g * 8 + c] * rstd;
    float be = beta[g * 8 + c] - mu * ga;
    union { unsigned short u[8]; uint4 v; } pk;
#pragma unroll
    for (int j = 0; j < 8; ++j) pk.u[j] = f2bf(vals[p * 8 + j] * ga + be);
    ((uint4*)lds)[idx] = pk.v;
  }
  __syncthreads();

  unsigned short* dstbase = g_hT + (size_t)b * 1024 * 256 + g * 8;
#pragma unroll
  for (int p = 0; p < 4; ++p) {
    int n = t + p * 256;
    union { unsigned short u[8]; uint4 v; } pk;
#pragma unroll
    for (int c = 0; c < 8; ++c) pk.u[c] = lds[c * 1024 + n];
    *(uint4*)(dstbase + (size_t)n * 256) = pk.v;
  }
}

// ---------------------------------------------------------------------------
// Kernel 2: channel GEMM  C[o][n] = sum_k W[o][k] * hT[n][k]  (K = 256)
// Round 13 (measured -21 us): QKV 96x256 tiles grid (4,8,16); proj 64x128
// grid (8,4,16); both = 512 blocks = 2 blocks/CU.
// Round 16 (measured NEUTRAL, kept): staging via global_load_lds width=16,
// linear LDS dest + pre-swizzled global source, XOR'd fragment reads.
// ---------------------------------------------------------------------------
template <int MODE>
__global__ __launch_bounds__(256, 2) void gemm_ct(
    const float* __restrict__ bias, const float* __restrict__ xres,
    float* __restrict__ outp) {
  constexpr int OT = (MODE == 0) ? 96 : 64;    // output rows per block
  constexpr int NT = (MODE == 0) ? 256 : 128;  // n cols per block
  constexpr int OI = OT / 16;                  // row frags (6 / 4)
  constexpr int NJ = NT / 64;                  // col frags per wave (4 / 2)
  constexpr int ASL = OT * 8;                  // A uint4 slots per kb
  constexpr int BSL = NT * 8;                  // B uint4 slots per kb

  const int n0 = blockIdx.x * NT;
  const int oty = blockIdx.y, o0 = oty * OT;
  const int b = blockIdx.z;
  const int t = threadIdx.x;
  const int w = t >> 6, lane = t & 63, quad = lane >> 4, l15 = lane & 15;

  __shared__ uint4 as[ASL];  // [row][kc ^ (row&7)]
  __shared__ uint4 bs[BSL];  // [row][kc ^ (row&7)]

  const uint4* Bv = (const uint4*)g_hT;
  const unsigned short* Wb = (MODE == 0) ? g_wq : g_wp;

  f32x4_t acc[OI][NJ];
#pragma unroll
  for (int i = 0; i < OI; ++i)
#pragma unroll
    for (int j = 0; j < NJ; ++j) acc[i][j] = (f32x4_t){0.f, 0.f, 0.f, 0.f};

  for (int kb = 0; kb < 4; ++kb) {
#pragma unroll
    for (int p = 0; p < ASL / 256; ++p) {
      int L = p * 256 + t;
      int row = L >> 3, kc = (L & 7) ^ (row & 7);
      gload_lds16(Wb + (size_t)(o0 + row) * 256 + kb * 64 + kc * 8,
                  &as[p * 256 + w * 64]);
    }
#pragma unroll
    for (int p = 0; p < BSL / 256; ++p) {
      int L = p * 256 + t;
      int row = L >> 3, kc = (L & 7) ^ (row & 7);
      gload_lds16(&Bv[(size_t)(b * 1024 + n0 + row) * 32 + kb * 8 + kc],
                  &bs[p * 256 + w * 64]);
    }
    __syncthreads();  // drains vmcnt (global_load_lds) before reads
#pragma unroll
    for (int kk = 0; kk < 2; ++kk) {
      int ch = kk * 4 + quad;
      const int sw = ch ^ (l15 & 7);
      bf16x8_t af[OI];
#pragma unroll
      for (int i = 0; i < OI; ++i)
        af[i] = __builtin_bit_cast(bf16x8_t, as[(i * 16 + l15) * 8 + sw]);
#pragma unroll
      for (int j = 0; j < NJ; ++j) {
        bf16x8_t bf = __builtin_bit_cast(
            bf16x8_t, bs[(w * (NT / 4) + j * 16 + l15) * 8 + sw]);
#pragma unroll
        for (int i = 0; i < OI; ++i)
          acc[i][j] = __builtin_amdgcn_mfma_f32_16x16x32_bf16(af[i], bf, acc[i][j], 0, 0, 0);
      }
    }
    __syncthreads();
  }

  float bi[OI][4];
#pragma unroll
  for (int i = 0; i < OI; ++i)
#pragma unroll
    for (int r = 0; r < 4; ++r) bi[i][r] = bias[o0 + i * 16 + quad * 4 + r];

  if (MODE == 0) {
#pragma unroll
    for (int i = 0; i < OI; ++i) {
      const int r0 = o0 + i * 16;
      const int head = r0 / 192;
      const int win = r0 - head * 192;
      const int type = win >> 6;         // 0=q 1=k 2=v
      const int d0 = (win & 63) + quad * 4;
      if (type < 2) {
        // Q gets the softmax scale folded in at the source (round 12).
        const float sc = (type == 0) ? 0.18033688f : 1.0f;  // 0.125 * log2(e)
        unsigned short* dst = (type == 0 ? g_qT : g_kT) + (size_t)(b * 4 + head) * 65536;
#pragma unroll
        for (int j = 0; j < NJ; ++j) {
          int n = n0 + w * 64 + j * 16 + l15;
          ushort4 pk;
          pk.x = f2bf((acc[i][j][0] + bi[i][0]) * sc);
          pk.y = f2bf((acc[i][j][1] + bi[i][1]) * sc);
          pk.z = f2bf((acc[i][j][2] + bi[i][2]) * sc);
          pk.w = f2bf((acc[i][j][3] + bi[i][3]) * sc);
          *(ushort4*)(dst + (size_t)n * 64 + d0) = pk;
        }
      } else {
        unsigned short* dst = g_vN + (size_t)(b * 4 + head) * 65536;
#pragma unroll
        for (int j = 0; j < NJ; ++j) {
          int n = n0 + w * 64 + j * 16 + l15;
#pragma unroll
          for (int r = 0; r < 4; ++r)
            dst[(size_t)(d0 + r) * 1024 + n] = f2bf(acc[i][j][r] + bi[i][r]);
        }
      }
    }
  } else {
#pragma unroll
    for (int i = 0; i < OI; ++i)
#pragma unroll
      for (int r = 0; r < 4; ++r) {
        int c = o0 + i * 16 + quad * 4 + r;
        const float* xr = xres + (((size_t)b * 256 + c) << 10);
        float* op = outp + (((size_t)b * 256 + c) << 10);
#pragma unroll
        for (int j = 0; j < NJ; ++j) {
          int n = n0 + w * 32 + j * 16 + l15;
          op[n] = acc[i][j][r] + bi[i][r] + xr[n];
        }
      }
  }
}

// ---------------------------------------------------------------------------
// Kernel 3: flash attention, transposed-P.
// Round 19: REVERTED round-18 SW pipeline (+2.1 us). Wave-split instead:
// same block-level structure as the proven r5 form (128 q-rows per block,
// 64x64 K/V tiles double-buffered, ONE barrier/iter, identical reuse) but
// 512 threads / 8 waves: each wave owns ONE 16-row q-tile (8+8 MFMAs/iter
// instead of 16+16). LDS 50.4 KB -> 2 blocks/CU x 8 waves = 4 waves/SIMD
// (was 2). Targets the measured latency-bound profile (MfmaUtil 9%) via
// TLP without the r17 reuse-loss trap (staged bytes per q-row unchanged).
// Softmax diet kept (r10/12). absmax 0.03125 << 0.1006 threshold.
// ---------------------------------------------------------------------------
__global__ __launch_bounds__(512) void attn_kernel() {
  const int bh = blockIdx.x;
  const int n0 = blockIdx.y * 128;
  const int t = threadIdx.x;
  const int w = t >> 6, lane = t & 63, quad = lane >> 4, l15 = lane & 15;
  const int b = bh >> 2, h = bh & 3;

  const uint4* qv = (const uint4*)(g_qT + (size_t)bh * 65536);
  const uint4* kv = (const uint4*)(g_kT + (size_t)bh * 65536);
  const uint4* vv = (const uint4*)(g_vN + (size_t)bh * 65536);

  __shared__ uint4 ks[2][512];  // [parity][chunk][row^chunk]  XOR-swizzled
  __shared__ uint4 vs[2][512];
  __shared__ __align__(16) unsigned short Pt[8 * 16 * 72];  // [wave][qrow][m']

  uint4 qr[2];
#pragma unroll
  for (int kk = 0; kk < 2; ++kk)
    qr[kk] = qv[(size_t)(n0 + w * 16 + l15) * 8 + kk * 4 + quad];

  // 512 threads stage the 64x64 tile exactly once: rr in 0..63, cc in 0..7.
  const int rr = t >> 3, cc = t & 7;
  uint4 kr = kv[rr * 8 + cc], vr = vv[rr * 128 + cc];

  f32x4_t OA[4];
#pragma unroll
  for (int i = 0; i < 4; ++i) OA[i] = (f32x4_t){0.f, 0.f, 0.f, 0.f};
  float rsum = 0.f;

  unsigned short* Pw = Pt + w * 1152;

#pragma unroll 1
  for (int mt = 0; mt < 16; ++mt) {
    uint4* kb = ks[mt & 1];
    uint4* vb = vs[mt & 1];
    kb[cc * 64 + (rr ^ cc)] = kr;
    vb[cc * 64 + (rr ^ cc)] = vr;
    __syncthreads();  // the ONLY barrier per iteration

    if (mt < 15) {
      int m1 = (mt + 1) * 64;
      kr = kv[(m1 + rr) * 8 + cc];
      vr = vv[rr * 128 + (mt + 1) * 8 + cc];
    }

    // ---- QK^T ----
    f32x4_t sA[4];
#pragma unroll
    for (int i = 0; i < 4; ++i) sA[i] = (f32x4_t){0.f, 0.f, 0.f, 0.f};
#pragma unroll
    for (int kk = 0; kk < 2; ++kk) {
      int ch = kk * 4 + quad;
      bf16x8_t bq = __builtin_bit_cast(bf16x8_t, qr[kk]);
#pragma unroll
      for (int ms = 0; ms < 4; ++ms) {
        bf16x8_t ak = __builtin_bit_cast(bf16x8_t, kb[ch * 64 + ((ms * 16 + l15) ^ ch)]);
        sA[ms] = __builtin_amdgcn_mfma_f32_16x16x32_bf16(ak, bq, sA[ms], 0, 0, 0);
      }
    }

    // ---- softmax: p = exp2(s) (Q pre-scaled); v_perm pack; Pt write ----
#pragma unroll
    for (int ms = 0; ms < 4; ++ms) {
      float a0 = exp2_hw(sA[ms][0]), a1 = exp2_hw(sA[ms][1]);
      float a2 = exp2_hw(sA[ms][2]), a3 = exp2_hw(sA[ms][3]);
      rsum += (a0 + a1) + (a2 + a3);
      uint2 pA;
      pA.x = pack_trunc(a0, a1);
      pA.y = pack_trunc(a2, a3);
      *(uint2*)(Pw + l15 * 72 + ms * 16 + quad * 4) = pA;
    }

    // ---- PV ----
#pragma unroll
    for (int km = 0; km < 2; ++km) {
      int ch = km * 4 + quad;
      bf16x8_t bp = *(const bf16x8_t*)(Pw + l15 * 72 + km * 32 + quad * 8);
#pragma unroll
      for (int ds = 0; ds < 4; ++ds) {
        bf16x8_t av = __builtin_bit_cast(bf16x8_t, vb[ch * 64 + ((ds * 16 + l15) ^ ch)]);
        OA[ds] = __builtin_amdgcn_mfma_f32_16x16x32_bf16(av, bp, OA[ds], 0, 0, 0);
      }
    }
  }

  rsum += __shfl_xor(rsum, 16, 64);
  rsum += __shfl_xor(rsum, 32, 64);
  const float inv = 1.f / rsum;

  unsigned short* dst = g_hT + ((size_t)b * 1024 + n0 + w * 16 + l15) * 256 + h * 64;
#pragma unroll
  for (int ds = 0; ds < 4; ++ds) {
    ushort4 pk;
    pk.x = f2bf(OA[ds][0] * inv); pk.y = f2bf(OA[ds][1] * inv);
    pk.z = f2bf(OA[ds][2] * inv); pk.w = f2bf(OA[ds][3] * inv);
    *(ushort4*)(dst + ds * 16 + quad * 4) = pk;
  }
}

// ---------------------------------------------------------------------------
extern "C" void kernel_launch(void* const* d_in, const int* in_sizes, int n_in,
                              void* d_out, int out_size, void* d_ws, size_t ws_size,
                              hipStream_t stream) {
  const float* x = (const float*)d_in[0];
  const float* gam = (const float*)d_in[1];
  const float* bet = (const float*)d_in[2];
  const float* qkv_w = (const float*)d_in[3];
  const float* qkv_b = (const float*)d_in[4];
  const float* pr_w = (const float*)d_in[5];
  const float* pr_b = (const float*)d_in[6];
  float* out = (float*)d_out;

  gn_kernel<<<512, 256, 0, stream>>>(x, gam, bet, qkv_w, pr_w);
  gemm_ct<0><<<dim3(4, 8, 16), 256, 0, stream>>>(qkv_b, nullptr, nullptr);
  attn_kernel<<<dim3(64, 8), 512, 0, stream>>>();
  gemm_ct<1><<<dim3(8, 4, 16), 256, 0, stream>>>(pr_b, x, out);
}